// Round 7
// baseline (76.942 us; speedup 1.0000x reference)
//
#include <hip/hip_runtime.h>

// SSIM loss, wave-autonomous vertical-first + XCD-aware block swizzle.
// x,y f32 [32,3,512,512] -> 2x2 pool (256x256) -> separable 11x11 Gaussian ->
// SSIM map 246x246 -> 1 - mean.
// Wave = (plane, 8-row output strip); 4 pooled cols/lane * 64 lanes = 256 cols.
// R5 post-mortem: duration tracks FETCH_SIZE at ~3 TB/s beyond-L2 rate ->
// traffic-bound. Strip halos (10/18 rows) are re-fetched because adjacent
// blocks land on different XCDs (incoherent L2s). Bijective XCD swizzle
// (744 = 8 x 93) puts consecutive strips on the same XCD -> halo hits L2.
// VGPR ~112 natural (no min-waves bound: gfx950 would target 64-VGPR bucket
// and spill -- R4 lesson).

#define KS 11
#define H 8
#define ROWS (H + KS - 1)        // 18 pooled rows per strip
#define NSTRIP 31                // 31*8 = 248 >= 246
#define NPLANE 96
#define NWAVE (NPLANE * NSTRIP)  // 2976
#define NBLOCK (NWAVE / 4)       // 744 = 8 * 93
#define CHUNK (NBLOCK / 8)       // 93 logical blocks per XCD
#define OUTD 246
#define BUFW 272                 // 256 + 16 pad cols (zeroed)
#define C1V 1e-4f
#define C2V 9e-4f

__device__ __forceinline__ void load_pool(const float* __restrict__ xp,
                                          const float* __restrict__ yp,
                                          int r0, int i, int lane,
                                          float (&px)[4], float (&py)[4]) {
    int pr = r0 + i; pr = pr > 255 ? 255 : pr;   // clamp; clamped rows feed masked outputs only
    const float* xr = xp + (size_t)(2 * pr) * 512 + 8 * lane;
    const float* yr = yp + (size_t)(2 * pr) * 512 + 8 * lane;
    float4 a0 = *(const float4*)xr;
    float4 a1 = *(const float4*)(xr + 4);
    float4 b0 = *(const float4*)(xr + 512);
    float4 b1 = *(const float4*)(xr + 516);
    float4 c0 = *(const float4*)yr;
    float4 c1 = *(const float4*)(yr + 4);
    float4 d0 = *(const float4*)(yr + 512);
    float4 d1 = *(const float4*)(yr + 516);
    px[0] = (a0.x + a0.y + b0.x + b0.y) * 0.25f;
    px[1] = (a0.z + a0.w + b0.z + b0.w) * 0.25f;
    px[2] = (a1.x + a1.y + b1.x + b1.y) * 0.25f;
    px[3] = (a1.z + a1.w + b1.z + b1.w) * 0.25f;
    py[0] = (c0.x + c0.y + d0.x + d0.y) * 0.25f;
    py[1] = (c0.z + c0.w + d0.z + d0.w) * 0.25f;
    py[2] = (c1.x + c1.y + d1.x + d1.y) * 0.25f;
    py[3] = (c1.z + c1.w + d1.z + d1.w) * 0.25f;
}

__device__ __forceinline__ void step_row(float* vb, const float (&wt)[KS],
                                         float (&rx)[KS][4], float (&ry)[KS][4],
                                         const float (&px)[4], const float (&py)[4],
                                         int lane, int ro, float& local) {
    // push newest row into slot KS-1
    #pragma unroll
    for (int c = 0; c < 4; ++c) { rx[KS - 1][c] = px[c]; ry[KS - 1][c] = py[c]; }

    // vertical 11-tap, products on the fly (all register, static idx)
    float vmx[4] = {0,0,0,0}, vmy[4] = {0,0,0,0};
    float vxx[4] = {0,0,0,0}, vyy[4] = {0,0,0,0}, vxy[4] = {0,0,0,0};
    #pragma unroll
    for (int k = 0; k < KS; ++k) {
        float wk = wt[k];
        #pragma unroll
        for (int c = 0; c < 4; ++c) {
            float xv = rx[k][c], yv = ry[k][c];
            vmx[c] += wk * xv;       vmy[c] += wk * yv;
            vxx[c] += wk * xv * xv;  vyy[c] += wk * yv * yv;
            vxy[c] += wk * xv * yv;
        }
    }

    // stage 5 V-sum planes to wave-private LDS (b128, conflict-free)
    *(float4*)(vb + 0 * BUFW + 4 * lane) = make_float4(vmx[0], vmx[1], vmx[2], vmx[3]);
    *(float4*)(vb + 1 * BUFW + 4 * lane) = make_float4(vmy[0], vmy[1], vmy[2], vmy[3]);
    *(float4*)(vb + 2 * BUFW + 4 * lane) = make_float4(vxx[0], vxx[1], vxx[2], vxx[3]);
    *(float4*)(vb + 3 * BUFW + 4 * lane) = make_float4(vyy[0], vyy[1], vyy[2], vyy[3]);
    *(float4*)(vb + 4 * BUFW + 4 * lane) = make_float4(vxy[0], vxy[1], vxy[2], vxy[3]);
    __builtin_amdgcn_wave_barrier();   // pin order; in-wave DS ops execute in order

    // horizontal 11-tap: window cols 4l..4l+13 via 4 aligned b128 per plane
    float hp[5][4];
    #pragma unroll
    for (int p = 0; p < 5; ++p) {
        const float* bp = vb + p * BUFW + 4 * lane;
        float4 q0 = *(const float4*)bp;
        float4 q1 = *(const float4*)(bp + 4);
        float4 q2 = *(const float4*)(bp + 8);
        float4 q3 = *(const float4*)(bp + 12);
        float win[16] = {q0.x, q0.y, q0.z, q0.w, q1.x, q1.y, q1.z, q1.w,
                         q2.x, q2.y, q2.z, q2.w, q3.x, q3.y, q3.z, q3.w};
        #pragma unroll
        for (int c = 0; c < 4; ++c) {
            float a = 0.f;
            #pragma unroll
            for (int j = 0; j < KS; ++j) a += wt[j] * win[c + j];
            hp[p][c] = a;
        }
    }

    if (ro < OUTD) {
        #pragma unroll
        for (int c = 0; c < 4; ++c) {
            int oc = 4 * lane + c;
            float mx = hp[0][c], my = hp[1][c];
            float mxx = mx * mx, myy = my * my, mxy = mx * my;
            float sxx = hp[2][c] - mxx, syy = hp[3][c] - myy, sxy = hp[4][c] - mxy;
            float num = (2.f * mxy + C1V) * (2.f * sxy + C2V);
            float den = (mxx + myy + C1V) * (sxx + syy + C2V);
            float ss = num / den;
            local += (oc < OUTD) ? ss : 0.f;
        }
    }

    // rotate ring (static movs; cheap vs latency we're hiding)
    #pragma unroll
    for (int k = 0; k < KS - 1; ++k) {
        #pragma unroll
        for (int c = 0; c < 4; ++c) { rx[k][c] = rx[k + 1][c]; ry[k][c] = ry[k + 1][c]; }
    }
}

__global__ __launch_bounds__(256) void ssim_wave(const float* __restrict__ x,
                                                 const float* __restrict__ y,
                                                 double* __restrict__ partial) {
    __shared__ float vbuf[4][5][BUFW];   // wave-private single buffer: 21.25 KB
    const int tid = threadIdx.x;
    const int wv = tid >> 6, lane = tid & 63;

    // Bijective XCD swizzle: hardware assigns XCD = blockIdx.x % 8 (round-robin).
    // Map so each XCD gets a CONTIGUOUS run of 93 logical blocks -> adjacent
    // strips share halo rows in that XCD's L2.
    const int lb = (blockIdx.x % 8) * CHUNK + (blockIdx.x / 8);

    const int gid = lb * 4 + wv;
    const int plane = gid / NSTRIP, strip = gid % NSTRIP;
    const int r0 = strip * H;
    const float* xp = x + (size_t)plane * (512 * 512);
    const float* yp = y + (size_t)plane * (512 * 512);

    float wt[KS];
    {
        float s = 0.f;
        #pragma unroll
        for (int i = 0; i < KS; ++i) {
            float d = (float)i - 5.f;
            wt[i] = expf(-d * d / 4.5f);   // 2*sigma^2 = 4.5
            s += wt[i];
        }
        float inv = 1.f / s;
        #pragma unroll
        for (int i = 0; i < KS; ++i) wt[i] *= inv;
    }

    // zero the 16 pad cols (reads beyond col 255 feed masked outputs)
    if (lane < BUFW - 256) {
        #pragma unroll
        for (int p = 0; p < 5; ++p)
            vbuf[wv][p][256 + lane] = 0.f;
    }
    __builtin_amdgcn_wave_barrier();

    // prime ring: rows 0..9 -> slots 0..9
    float rx[KS][4], ry[KS][4];
    #pragma unroll
    for (int i = 0; i < KS - 1; ++i)
        load_pool(xp, yp, r0, i, lane, rx[i], ry[i]);

    float cpx[4], cpy[4], npx[4], npy[4];
    load_pool(xp, yp, r0, KS - 1, lane, cpx, cpy);
    float local = 0.f;
    float* vb = &vbuf[wv][0][0];

    #pragma unroll 1
    for (int i = KS - 1; i < ROWS; ++i) {
        load_pool(xp, yp, r0, i + 1, lane, npx, npy);   // prefetch next row (clamped at end)
        step_row(vb, wt, rx, ry, cpx, cpy, lane, r0 + i - (KS - 1), local);
        #pragma unroll
        for (int c = 0; c < 4; ++c) { cpx[c] = npx[c]; cpy[c] = npy[c]; }
    }

    // wave reduce, one partial per wave
    #pragma unroll
    for (int off = 32; off > 0; off >>= 1)
        local += __shfl_down(local, off, 64);
    if (lane == 0) partial[gid] = (double)local;
}

__global__ __launch_bounds__(256) void ssim_finalize(const double* __restrict__ partial,
                                                     float* __restrict__ out) {
    const int tid = threadIdx.x;
    double s = 0.0;
    for (int i = tid; i < NWAVE; i += 256) s += partial[i];
    #pragma unroll
    for (int off = 32; off > 0; off >>= 1)
        s += __shfl_down(s, off, 64);
    __shared__ double sd[4];
    if ((tid & 63) == 0) sd[tid >> 6] = s;
    __syncthreads();
    if (tid == 0) {
        double total = sd[0] + sd[1] + sd[2] + sd[3];
        const double n = (double)NPLANE * OUTD * OUTD;   // 5,809,536
        out[0] = (float)(1.0 - total / n);
    }
}

extern "C" void kernel_launch(void* const* d_in, const int* in_sizes, int n_in,
                              void* d_out, int out_size, void* d_ws, size_t ws_size,
                              hipStream_t stream) {
    const float* x = (const float*)d_in[0];
    const float* y = (const float*)d_in[1];
    float* out = (float*)d_out;
    double* partial = (double*)d_ws;   // NWAVE * 8 = 23.25 KiB

    ssim_wave<<<NBLOCK, 256, 0, stream>>>(x, y, partial);
    ssim_finalize<<<1, 256, 0, stream>>>(partial, out);
}

// Round 8
// 65.573 us; speedup vs baseline: 1.1734x; 1.1734x over previous
//
#include <hip/hip_runtime.h>

// SSIM loss, wave-autonomous vertical-first + software-pipelined loads.
// x,y f32 [32,3,512,512] -> 2x2 pool (256x256) -> separable 11x11 Gaussian ->
// SSIM map 246x246 -> 1 - mean.
// Wave = (plane, 12-row output strip); 4 pooled cols/lane * 64 lanes = 256 cols.
// R6 post-mortem: load_pool issued+consumed loads back-to-back -> vmcnt(0) stall
// of full LLC latency every row-step (VALUBusy 27%). Fix: issue row i+1 into raw
// float4 regs, compute step_row(i), THEN pool the raws -> wait lands after compute.
// Ring of pooled rows stays in registers (rotation, unroll-1 loop).
// No launch_bounds min-waves (R4 lesson: gfx950 targets 64-VGPR bucket -> spill).

#define KS 11
#define H 12
#define ROWS (H + KS - 1)        // 22 pooled rows per strip
#define NSTRIP 21                // 21*12 = 252 >= 246
#define NPLANE 96
#define NWAVE (NPLANE * NSTRIP)  // 2016
#define NBLOCK (NWAVE / 4)       // 504
#define OUTD 246
#define BUFW 272                 // 256 + 16 pad cols (zeroed)
#define C1V 1e-4f
#define C2V 9e-4f

__device__ __forceinline__ void load_pool(const float* __restrict__ xp,
                                          const float* __restrict__ yp,
                                          int r0, int i, int lane,
                                          float (&px)[4], float (&py)[4]) {
    int pr = r0 + i; pr = pr > 255 ? 255 : pr;
    const float* xr = xp + (size_t)(2 * pr) * 512 + 8 * lane;
    const float* yr = yp + (size_t)(2 * pr) * 512 + 8 * lane;
    float4 a0 = *(const float4*)xr;
    float4 a1 = *(const float4*)(xr + 4);
    float4 b0 = *(const float4*)(xr + 512);
    float4 b1 = *(const float4*)(xr + 516);
    float4 c0 = *(const float4*)yr;
    float4 c1 = *(const float4*)(yr + 4);
    float4 d0 = *(const float4*)(yr + 512);
    float4 d1 = *(const float4*)(yr + 516);
    px[0] = (a0.x + a0.y + b0.x + b0.y) * 0.25f;
    px[1] = (a0.z + a0.w + b0.z + b0.w) * 0.25f;
    px[2] = (a1.x + a1.y + b1.x + b1.y) * 0.25f;
    px[3] = (a1.z + a1.w + b1.z + b1.w) * 0.25f;
    py[0] = (c0.x + c0.y + d0.x + d0.y) * 0.25f;
    py[1] = (c0.z + c0.w + d0.z + d0.w) * 0.25f;
    py[2] = (c1.x + c1.y + d1.x + d1.y) * 0.25f;
    py[3] = (c1.z + c1.w + d1.z + d1.w) * 0.25f;
}

// issue-only: raw 16B loads, no consumption (keeps vmcnt wait out of the way)
__device__ __forceinline__ void issue_row(const float* __restrict__ xp,
                                          const float* __restrict__ yp,
                                          int r0, int i, int lane,
                                          float4 (&rawx)[4], float4 (&rawy)[4]) {
    int pr = r0 + i; pr = pr > 255 ? 255 : pr;
    const float* xr = xp + (size_t)(2 * pr) * 512 + 8 * lane;
    const float* yr = yp + (size_t)(2 * pr) * 512 + 8 * lane;
    rawx[0] = *(const float4*)xr;
    rawx[1] = *(const float4*)(xr + 4);
    rawx[2] = *(const float4*)(xr + 512);
    rawx[3] = *(const float4*)(xr + 516);
    rawy[0] = *(const float4*)yr;
    rawy[1] = *(const float4*)(yr + 4);
    rawy[2] = *(const float4*)(yr + 512);
    rawy[3] = *(const float4*)(yr + 516);
}

__device__ __forceinline__ void pool_raw(const float4 (&rawx)[4], const float4 (&rawy)[4],
                                         float (&px)[4], float (&py)[4]) {
    px[0] = (rawx[0].x + rawx[0].y + rawx[2].x + rawx[2].y) * 0.25f;
    px[1] = (rawx[0].z + rawx[0].w + rawx[2].z + rawx[2].w) * 0.25f;
    px[2] = (rawx[1].x + rawx[1].y + rawx[3].x + rawx[3].y) * 0.25f;
    px[3] = (rawx[1].z + rawx[1].w + rawx[3].z + rawx[3].w) * 0.25f;
    py[0] = (rawy[0].x + rawy[0].y + rawy[2].x + rawy[2].y) * 0.25f;
    py[1] = (rawy[0].z + rawy[0].w + rawy[2].z + rawy[2].w) * 0.25f;
    py[2] = (rawy[1].x + rawy[1].y + rawy[3].x + rawy[3].y) * 0.25f;
    py[3] = (rawy[1].z + rawy[1].w + rawy[3].z + rawy[3].w) * 0.25f;
}

__device__ __forceinline__ void step_row(float* vb, const float (&wt)[KS],
                                         float (&rx)[KS][4], float (&ry)[KS][4],
                                         const float (&px)[4], const float (&py)[4],
                                         int lane, int ro, float& local) {
    // push newest row into slot KS-1
    #pragma unroll
    for (int c = 0; c < 4; ++c) { rx[KS - 1][c] = px[c]; ry[KS - 1][c] = py[c]; }

    // vertical 11-tap, products on the fly (all register, static idx)
    float vmx[4] = {0,0,0,0}, vmy[4] = {0,0,0,0};
    float vxx[4] = {0,0,0,0}, vyy[4] = {0,0,0,0}, vxy[4] = {0,0,0,0};
    #pragma unroll
    for (int k = 0; k < KS; ++k) {
        float wk = wt[k];
        #pragma unroll
        for (int c = 0; c < 4; ++c) {
            float xv = rx[k][c], yv = ry[k][c];
            vmx[c] += wk * xv;       vmy[c] += wk * yv;
            vxx[c] += wk * xv * xv;  vyy[c] += wk * yv * yv;
            vxy[c] += wk * xv * yv;
        }
    }

    // stage 5 V-sum planes to wave-private LDS (b128)
    *(float4*)(vb + 0 * BUFW + 4 * lane) = make_float4(vmx[0], vmx[1], vmx[2], vmx[3]);
    *(float4*)(vb + 1 * BUFW + 4 * lane) = make_float4(vmy[0], vmy[1], vmy[2], vmy[3]);
    *(float4*)(vb + 2 * BUFW + 4 * lane) = make_float4(vxx[0], vxx[1], vxx[2], vxx[3]);
    *(float4*)(vb + 3 * BUFW + 4 * lane) = make_float4(vyy[0], vyy[1], vyy[2], vyy[3]);
    *(float4*)(vb + 4 * BUFW + 4 * lane) = make_float4(vxy[0], vxy[1], vxy[2], vxy[3]);
    __builtin_amdgcn_wave_barrier();   // pin order; in-wave DS ops execute in order

    // horizontal 11-tap: window cols 4l..4l+13 via 4 aligned b128 per plane
    float hp[5][4];
    #pragma unroll
    for (int p = 0; p < 5; ++p) {
        const float* bp = vb + p * BUFW + 4 * lane;
        float4 q0 = *(const float4*)bp;
        float4 q1 = *(const float4*)(bp + 4);
        float4 q2 = *(const float4*)(bp + 8);
        float4 q3 = *(const float4*)(bp + 12);
        float win[16] = {q0.x, q0.y, q0.z, q0.w, q1.x, q1.y, q1.z, q1.w,
                         q2.x, q2.y, q2.z, q2.w, q3.x, q3.y, q3.z, q3.w};
        #pragma unroll
        for (int c = 0; c < 4; ++c) {
            float a = 0.f;
            #pragma unroll
            for (int j = 0; j < KS; ++j) a += wt[j] * win[c + j];
            hp[p][c] = a;
        }
    }

    if (ro < OUTD) {
        #pragma unroll
        for (int c = 0; c < 4; ++c) {
            int oc = 4 * lane + c;
            float mx = hp[0][c], my = hp[1][c];
            float mxx = mx * mx, myy = my * my, mxy = mx * my;
            float sxx = hp[2][c] - mxx, syy = hp[3][c] - myy, sxy = hp[4][c] - mxy;
            float num = (2.f * mxy + C1V) * (2.f * sxy + C2V);
            float den = (mxx + myy + C1V) * (sxx + syy + C2V);
            float ss = num / den;
            local += (oc < OUTD) ? ss : 0.f;
        }
    }

    // rotate ring (static movs)
    #pragma unroll
    for (int k = 0; k < KS - 1; ++k) {
        #pragma unroll
        for (int c = 0; c < 4; ++c) { rx[k][c] = rx[k + 1][c]; ry[k][c] = ry[k + 1][c]; }
    }
}

__global__ __launch_bounds__(256) void ssim_wave(const float* __restrict__ x,
                                                 const float* __restrict__ y,
                                                 double* __restrict__ partial) {
    __shared__ float vbuf[4][5][BUFW];   // wave-private single buffer: 21.25 KB
    const int tid = threadIdx.x;
    const int wv = tid >> 6, lane = tid & 63;
    const int gid = blockIdx.x * 4 + wv;
    const int plane = gid / NSTRIP, strip = gid % NSTRIP;
    const int r0 = strip * H;
    const float* xp = x + (size_t)plane * (512 * 512);
    const float* yp = y + (size_t)plane * (512 * 512);

    float wt[KS];
    {
        float s = 0.f;
        #pragma unroll
        for (int i = 0; i < KS; ++i) {
            float d = (float)i - 5.f;
            wt[i] = expf(-d * d / 4.5f);   // 2*sigma^2 = 4.5
            s += wt[i];
        }
        float inv = 1.f / s;
        #pragma unroll
        for (int i = 0; i < KS; ++i) wt[i] *= inv;
    }

    // zero the 16 pad cols (reads beyond col 255 feed masked outputs)
    if (lane < BUFW - 256) {
        #pragma unroll
        for (int p = 0; p < 5; ++p)
            vbuf[wv][p][256 + lane] = 0.f;
    }
    __builtin_amdgcn_wave_barrier();

    // prime ring: rows 0..9 -> slots 0..9 (TLP across resident waves hides this)
    float rx[KS][4], ry[KS][4];
    #pragma unroll
    for (int i = 0; i < KS - 1; ++i)
        load_pool(xp, yp, r0, i, lane, rx[i], ry[i]);

    float cpx[4], cpy[4];
    load_pool(xp, yp, r0, KS - 1, lane, cpx, cpy);

    float local = 0.f;
    float* vb = &vbuf[wv][0][0];
    float4 rawx[4], rawy[4];

    #pragma unroll 1
    for (int i = KS - 1; i < ROWS; ++i) {
        issue_row(xp, yp, r0, i + 1, lane, rawx, rawy);   // issue-only; no consume
        step_row(vb, wt, rx, ry, cpx, cpy, lane, r0 + i - (KS - 1), local);
        pool_raw(rawx, rawy, cpx, cpy);                   // vmcnt wait lands here
    }

    // wave reduce, one partial per wave
    #pragma unroll
    for (int off = 32; off > 0; off >>= 1)
        local += __shfl_down(local, off, 64);
    if (lane == 0) partial[gid] = (double)local;
}

__global__ __launch_bounds__(256) void ssim_finalize(const double* __restrict__ partial,
                                                     float* __restrict__ out) {
    const int tid = threadIdx.x;
    double s = 0.0;
    for (int i = tid; i < NWAVE; i += 256) s += partial[i];
    #pragma unroll
    for (int off = 32; off > 0; off >>= 1)
        s += __shfl_down(s, off, 64);
    __shared__ double sd[4];
    if ((tid & 63) == 0) sd[tid >> 6] = s;
    __syncthreads();
    if (tid == 0) {
        double total = sd[0] + sd[1] + sd[2] + sd[3];
        const double n = (double)NPLANE * OUTD * OUTD;   // 5,809,536
        out[0] = (float)(1.0 - total / n);
    }
}

extern "C" void kernel_launch(void* const* d_in, const int* in_sizes, int n_in,
                              void* d_out, int out_size, void* d_ws, size_t ws_size,
                              hipStream_t stream) {
    const float* x = (const float*)d_in[0];
    const float* y = (const float*)d_in[1];
    float* out = (float*)d_out;
    double* partial = (double*)d_ws;   // NWAVE * 8 = 15.75 KiB

    ssim_wave<<<NBLOCK, 256, 0, stream>>>(x, y, partial);
    ssim_finalize<<<1, 256, 0, stream>>>(partial, out);
}